// Round 1
// baseline (140.735 us; speedup 1.0000x reference)
//
#include <hip/hip_runtime.h>

// Cost volume: out (B, 2C, D, H, W), fp32
//   c <  C : out = (w>=d) ? ref[b][c][h][w]     : 0
//   c >= C : out = (w>=d) ? tgt[b][c-C][h][w-d] : 0
// B=4, C=32, D=48, H=64, W=128. Output ~402.7 MB -> write-BW bound.

constexpr int CV_B = 4;
constexpr int CV_C = 32;
constexpr int CV_H = 64;
constexpr int CV_W = 128;
constexpr int CV_D = 48;

// block = 256 threads = 8 rows x 32 float4 (W=128 floats = 32 float4)
// grid  = (H/8, D, B*2C)  -> no integer div/mod anywhere
__global__ __launch_bounds__(256) void cost_volume_kernel(
    const float* __restrict__ ref,
    const float* __restrict__ tgt,
    float4* __restrict__ out)
{
    const int w4   = threadIdx.x & 31;        // float4 index within row [0,32)
    const int hsub = threadIdx.x >> 5;        // row within block [0,8)
    const int h    = (blockIdx.x << 3) + hsub;
    const int d    = blockIdx.y;
    const int bc   = blockIdx.z;              // b*64 + c2, c2 in [0,64)
    const int b    = bc >> 6;
    const int c2   = bc & 63;

    const bool is_tgt = (c2 >= CV_C);
    const int  c      = is_tgt ? (c2 - CV_C) : c2;

    // source row base: (b*C + c)*H + h rows of W floats
    const float* __restrict__ src =
        (is_tgt ? tgt : ref) + (((long long)(b * CV_C + c)) * CV_H + h) * CV_W;

    const int w0 = w4 << 2;                   // first w of this float4

    float r[4];
#pragma unroll
    for (int j = 0; j < 4; ++j) {
        const int w = w0 + j;
        float v = 0.0f;
        if (w >= d) {
            v = is_tgt ? src[w - d] : src[w];
        }
        r[j] = v;
    }

    float4 v4;
    v4.x = r[0]; v4.y = r[1]; v4.z = r[2]; v4.w = r[3];

    // out flat float4 index: (((bc*D + d)*H + h)*32 + w4)
    const long long o4 =
        ((((long long)bc * CV_D + d) * CV_H + h) << 5) + w4;
    out[o4] = v4;
}

extern "C" void kernel_launch(void* const* d_in, const int* in_sizes, int n_in,
                              void* d_out, int out_size, void* d_ws, size_t ws_size,
                              hipStream_t stream)
{
    const float* ref = (const float*)d_in[0];
    const float* tgt = (const float*)d_in[1];
    float4* out = (float4*)d_out;

    dim3 block(256);
    dim3 grid(CV_H / 8, CV_D, CV_B * 2 * CV_C);
    cost_volume_kernel<<<grid, block, 0, stream>>>(ref, tgt, out);
}

// Round 3
// 69.759 us; speedup vs baseline: 2.0174x; 2.0174x over previous
//
#include <hip/hip_runtime.h>

// Cost volume: out (B, 2C, D, H, W), fp32
//   c <  C : out = (w>=d) ? ref[b][c][h][w]     : 0
//   c >= C : out = (w>=d) ? tgt[b][c-C][h][w-d] : 0
// B=4, C=32, H=64, W=128, D=48. Output ~402.7 MB -> write-BW bound.
//
// R2: same as R1 but with clang ext_vector_type(4) so
// __builtin_nontemporal_store accepts the pointer.

constexpr int CV_B = 4;
constexpr int CV_C = 32;
constexpr int CV_H = 64;
constexpr int CV_W = 128;
constexpr int CV_D = 48;

typedef float floatx4 __attribute__((ext_vector_type(4)));

__global__ __launch_bounds__(256) void cost_volume_kernel(
    const float* __restrict__ ref,
    const float* __restrict__ tgt,
    floatx4* __restrict__ out)
{
    const int w4 = threadIdx.x & 31;          // float4 index within row [0,32)
    const int d0 = threadIdx.x >> 5;          // base disparity [0,8)
    const int h  = blockIdx.x & (CV_H - 1);
    const int bc = blockIdx.x >> 6;           // b*64 + c2, c2 in [0,64)
    const int b  = bc >> 6;
    const int c2 = bc & 63;

    const bool is_tgt = (c2 >= CV_C);
    const int  c      = is_tgt ? (c2 - CV_C) : c2;

    const float* __restrict__ src =
        (is_tgt ? tgt : ref) + ((b * CV_C + c) * CV_H + h) * CV_W;

    const int w0 = w4 << 2;                   // first w of this float4

    // out float4 index for d = d0: ((bc*D + d0)*H + h)*32 + w4
    floatx4* __restrict__ o =
        out + (((bc * CV_D + d0) * CV_H + h) << 5) + w4;
    constexpr int OSTRIDE = 8 * CV_H * (CV_W / 4);   // d += 8, in float4 units

    if (!is_tgt) {
        // ref half: same source float4 for every d, just re-mask.
        const floatx4 v = *reinterpret_cast<const floatx4*>(src + w0);
#pragma unroll
        for (int k = 0; k < 6; ++k) {
            const int d = d0 + (k << 3);
            floatx4 r;
            r.x = (w0 + 0 >= d) ? v.x : 0.0f;
            r.y = (w0 + 1 >= d) ? v.y : 0.0f;
            r.z = (w0 + 2 >= d) ? v.z : 0.0f;
            r.w = (w0 + 3 >= d) ? v.w : 0.0f;
            __builtin_nontemporal_store(r, o + k * OSTRIDE);
        }
    } else {
        // tgt half: shifted window per d.
#pragma unroll
        for (int k = 0; k < 6; ++k) {
            const int d = d0 + (k << 3);
            const int s = w0 - d;             // source start for this float4
            floatx4 r;
            if (s >= 0) {
                // dword-aligned 16B load (gfx9 dwordx4 needs only 4B align)
                r = *reinterpret_cast<const floatx4*>(src + s);
            } else {
                floatx4 a;
#pragma unroll
                for (int j = 0; j < 4; ++j)
                    a[j] = (s + j >= 0) ? src[s + j] : 0.0f;
                r = a;
            }
            __builtin_nontemporal_store(r, o + k * OSTRIDE);
        }
    }
}

extern "C" void kernel_launch(void* const* d_in, const int* in_sizes, int n_in,
                              void* d_out, int out_size, void* d_ws, size_t ws_size,
                              hipStream_t stream)
{
    const float* ref = (const float*)d_in[0];
    const float* tgt = (const float*)d_in[1];
    floatx4* out = (floatx4*)d_out;

    dim3 block(256);
    dim3 grid(CV_B * 2 * CV_C * CV_H);        // one block per (bc, h) = 16384
    cost_volume_kernel<<<grid, block, 0, stream>>>(ref, tgt, out);
}